// Round 4
// baseline (92.600 us; speedup 1.0000x reference)
//
#include <hip/hip_runtime.h>
#include <hip/hip_bf16.h>

// Paged-KV index construction.
// out[b*P + p] = (p < ceil(len[b]/64)) ? req_to_token[pool[b], clip(start[b]+p*64)] >> 6 : 0
// All integer inputs arrive as int32; output read back as int32.
//
// Mapping: one block per request row (b = blockIdx.x, wave-uniform -> scalar
// loads for the per-row scalars), 128 threads x 4 pages each = 512 pages.
// Loads are skipped entirely for invalid pages (saves ~half the scattered
// fetch traffic on average); 4 independent scattered loads per thread give
// MLP; output stored as one int4 per thread (fully coalesced 16 B/lane).

#define PAGE_SHIFT 6
#define PAGE_SIZE  64

__global__ void kv_indices_kernel(const int* __restrict__ req_to_token,
                                  const int* __restrict__ req_pool_indices,
                                  const int* __restrict__ page_kernel_lens,
                                  const int* __restrict__ kv_start_idx,
                                  int* __restrict__ out,
                                  int max_ctx) {
    const int b  = blockIdx.x;
    const int p0 = threadIdx.x << 2;           // 4 pages per thread

    const int kv_start  = kv_start_idx[b];
    const int len       = page_kernel_lens[b];
    const int num_paged = (len + 63) >> PAGE_SHIFT;
    const long long rowbase = (long long)req_pool_indices[b] * (long long)max_ctx;

    int r[4];
    #pragma unroll
    for (int j = 0; j < 4; ++j) {
        const int p = p0 + j;
        int v = 0;
        if (p < num_paged) {
            int off = kv_start + (p << PAGE_SHIFT);
            off = min(max(off, 0), max_ctx - 1);
            v = req_to_token[rowbase + off] >> PAGE_SHIFT;
        }
        r[j] = v;
    }

    int4 packed = make_int4(r[0], r[1], r[2], r[3]);
    reinterpret_cast<int4*>(out)[(size_t)b * blockDim.x + threadIdx.x] = packed;
}

extern "C" void kernel_launch(void* const* d_in, const int* in_sizes, int n_in,
                              void* d_out, int out_size, void* d_ws, size_t ws_size,
                              hipStream_t stream) {
    const int* req_to_token     = (const int*)d_in[0];
    const int* req_pool_indices = (const int*)d_in[1];
    const int* page_kernel_lens = (const int*)d_in[2];
    const int* kv_start_idx     = (const int*)d_in[3];
    int*       out              = (int*)d_out;

    int batch         = in_sizes[1];                 // 256
    int max_num_pages = out_size / batch;            // 512
    int max_ctx       = max_num_pages * PAGE_SIZE;   // 32768
    (void)ws_size; (void)d_ws; (void)n_in;

    int block = max_num_pages / 4;                   // 128 threads, 4 pages each
    kv_indices_kernel<<<batch, block, 0, stream>>>(
        req_to_token, req_pool_indices, page_kernel_lens, kv_start_idx,
        out, max_ctx);
}